// Round 1
// baseline (206.393 us; speedup 1.0000x reference)
//
#include <hip/hip_runtime.h>

#define LREL(x) ((x) > 0.0f ? (x) : 0.01f * (x))

constexpr int NNODE = 78;

// ---------------------------------------------------------------------------
// Kernel 1: build incoming-edge CSR from edge_index [2, E] (int32).
// row_ptr[79], csr_src[E] written to workspace. One block.
// ---------------------------------------------------------------------------
__global__ void build_csr_kernel(const int* __restrict__ ei, int E,
                                 int* __restrict__ row_ptr,
                                 int* __restrict__ csr_src) {
    __shared__ int cnt[NNODE];
    __shared__ int cur[NNODE];
    int tid = threadIdx.x;
    if (tid < NNODE) cnt[tid] = 0;
    __syncthreads();
    for (int e = tid; e < E; e += blockDim.x)
        atomicAdd(&cnt[ei[E + e]], 1);          // tgt = ei[1][e]
    __syncthreads();
    if (tid == 0) {
        int acc = 0;
        for (int n = 0; n < NNODE; ++n) {
            row_ptr[n] = acc;
            cur[n]     = acc;
            acc += cnt[n];
        }
        row_ptr[NNODE] = acc;
    }
    __syncthreads();
    for (int e = tid; e < E; e += blockDim.x) {
        int t   = ei[E + e];
        int pos = atomicAdd(&cur[t], 1);
        csr_src[pos] = ei[e];                   // src = ei[0][e]
    }
}

// ---------------------------------------------------------------------------
// Block-wide (128-thread / 2-wave) sum reduction.
// ---------------------------------------------------------------------------
__device__ __forceinline__ float block_sum(float v, float* s_tmp) {
#pragma unroll
    for (int o = 32; o > 0; o >>= 1) v += __shfl_down(v, o, 64);
    int lane = threadIdx.x & 63;
    int wv   = threadIdx.x >> 6;
    __syncthreads();                 // protect s_tmp reuse across calls
    if (lane == 0) s_tmp[wv] = v;
    __syncthreads();
    return s_tmp[0] + s_tmp[1];
}

// ---------------------------------------------------------------------------
// Kernel 2: fully fused forward, one block (128 threads) per batch graph.
// ---------------------------------------------------------------------------
__global__ __launch_bounds__(128) void graph_fused_kernel(
    const float* __restrict__ cli,    // [B,58]
    const float* __restrict__ radio,  // [B,384]
    const float* __restrict__ ln1g, const float* __restrict__ ln1b,
    const float* __restrict__ encw, const float* __restrict__ encb,
    const float* __restrict__ q1w, const float* __restrict__ q1b,
    const float* __restrict__ k1w, const float* __restrict__ k1b,
    const float* __restrict__ v1w, const float* __restrict__ v1b,
    const float* __restrict__ s1w, const float* __restrict__ s1b,
    const float* __restrict__ q2w, const float* __restrict__ q2b,
    const float* __restrict__ k2w, const float* __restrict__ k2b,
    const float* __restrict__ v2w, const float* __restrict__ v2b,
    const float* __restrict__ s2w, const float* __restrict__ s2b,
    const float* __restrict__ ln2g, const float* __restrict__ ln2b,
    const float* __restrict__ clsw, const float* __restrict__ clsb,
    const int* __restrict__ row_ptr, const int* __restrict__ csr_src,
    int E, float* __restrict__ out) {

    extern __shared__ int s_csr[];         // [E]
    __shared__ float s_xn[384];            // normalized radio row
    __shared__ float s_part[128];          // encoder partials
    __shared__ float s_x[NNODE];           // node features (layer-0 input)
    __shared__ float s_y[NNODE * 5];       // layer-1 output, stride 5 (bank-conflict pad)
    __shared__ float s_z[NNODE];           // layer-2 output
    __shared__ int   s_rp[NNODE + 1];
    __shared__ float s_tmp[2];

    const int tid = threadIdx.x;
    const int b   = blockIdx.x;

    // stage CSR into LDS
    for (int i = tid; i < E; i += 128) s_csr[i] = csr_src[i];
    if (tid < NNODE + 1) s_rp[tid] = row_ptr[tid];

    // ---- LayerNorm(radio[b]) ----
    const float* rrow = radio + (size_t)b * 384;
    float v0 = rrow[tid];
    float v1 = rrow[tid + 128];
    float v2 = rrow[tid + 256];
    float tot   = block_sum(v0 + v1 + v2, s_tmp);
    float totsq = block_sum(v0 * v0 + v1 * v1 + v2 * v2, s_tmp);
    float mean = tot * (1.0f / 384.0f);
    float var  = totsq * (1.0f / 384.0f) - mean * mean;
    float rstd = rsqrtf(var + 1e-5f);
    s_xn[tid]       = (v0 - mean) * rstd * ln1g[tid]       + ln1b[tid];
    s_xn[tid + 128] = (v1 - mean) * rstd * ln1g[tid + 128] + ln1b[tid + 128];
    s_xn[tid + 256] = (v2 - mean) * rstd * ln1g[tid + 256] + ln1b[tid + 256];
    if (tid < 58) s_x[tid] = cli[(size_t)b * 58 + tid];
    __syncthreads();

    // ---- Encoder: h[j] = dot(xn, encw[j,:]) + encb[j], j in [0,20) ----
    if (tid < 120) {
        const int j = tid % 20, c = tid / 20;
        const float* w  = encw + j * 384 + c * 64;
        const float* xp = s_xn + c * 64;
        float p = 0.0f;
#pragma unroll 16
        for (int i = 0; i < 64; ++i) p = fmaf(xp[i], w[i], p);
        s_part[tid] = p;
    }
    __syncthreads();
    if (tid < 20) {
        float hv = encb[tid];
#pragma unroll
        for (int c = 0; c < 6; ++c) hv += s_part[c * 20 + tid];
        s_x[58 + tid] = LREL(hv);
    }
    __syncthreads();

    // ---- TransformerConv layer 1: in=1, H=4, C=1 ----
    if (tid < NNODE) {
        const int n  = tid;
        const float xv = s_x[n];
        float qa[4], cc[4], m[4], den[4], acc[4];
#pragma unroll
        for (int h = 0; h < 4; ++h) {
            float qh = xv * q1w[h] + q1b[h];
            qa[h] = qh * k1w[h];          // alpha = qa*x[src] + cc
            cc[h] = qh * k1b[h];
            m[h]  = -1e30f;
            den[h] = 0.0f;
            acc[h] = 0.0f;
        }
        const int beg = s_rp[n], end = s_rp[n + 1];
        for (int i = beg; i < end; ++i) {
            float t = s_x[s_csr[i]];
#pragma unroll
            for (int h = 0; h < 4; ++h) m[h] = fmaxf(m[h], fmaf(qa[h], t, cc[h]));
        }
        for (int i = beg; i < end; ++i) {
            float t = s_x[s_csr[i]];
#pragma unroll
            for (int h = 0; h < 4; ++h) {
                float al = fmaf(qa[h], t, cc[h]);
                float e  = __expf(al - m[h]);
                den[h] += e;
                acc[h] = fmaf(e, fmaf(v1w[h], t, v1b[h]), acc[h]);
            }
        }
#pragma unroll
        for (int h = 0; h < 4; ++h) {
            float o = acc[h] / den[h] + fmaf(xv, s1w[h], s1b[h]);
            s_y[n * 5 + h] = LREL(o);
        }
    }
    __syncthreads();

    // ---- TransformerConv layer 2: in=4, H=1, C=1 ----
    if (tid < NNODE) {
        const int n = tid;
        float y0 = s_y[n * 5 + 0], y1 = s_y[n * 5 + 1];
        float y2 = s_y[n * 5 + 2], y3 = s_y[n * 5 + 3];
        float q = q2b[0] + y0 * q2w[0] + y1 * q2w[1] + y2 * q2w[2] + y3 * q2w[3];
        const int beg = s_rp[n], end = s_rp[n + 1];
        float m = -1e30f;
        for (int i = beg; i < end; ++i) {
            const int s = s_csr[i] * 5;
            float k = k2b[0] + s_y[s] * k2w[0] + s_y[s + 1] * k2w[1]
                             + s_y[s + 2] * k2w[2] + s_y[s + 3] * k2w[3];
            m = fmaxf(m, q * k);
        }
        float den = 0.0f, acc = 0.0f;
        for (int i = beg; i < end; ++i) {
            const int s = s_csr[i] * 5;
            float k = k2b[0] + s_y[s] * k2w[0] + s_y[s + 1] * k2w[1]
                             + s_y[s + 2] * k2w[2] + s_y[s + 3] * k2w[3];
            float v = v2b[0] + s_y[s] * v2w[0] + s_y[s + 1] * v2w[1]
                             + s_y[s + 2] * v2w[2] + s_y[s + 3] * v2w[3];
            float e = __expf(q * k - m);
            den += e;
            acc = fmaf(e, v, acc);
        }
        float o = acc / den + s2b[0] + y0 * s2w[0] + y1 * s2w[1]
                            + y2 * s2w[2] + y3 * s2w[3];
        s_z[n] = LREL(o);
    }
    __syncthreads();

    // ---- final LayerNorm(78) + classifier (2 outputs) ----
    float zv = (tid < NNODE) ? s_z[tid] : 0.0f;
    float zs  = block_sum(zv, s_tmp);
    float zsq = block_sum(zv * zv, s_tmp);
    float zm  = zs * (1.0f / 78.0f);
    float zvr = zsq * (1.0f / 78.0f) - zm * zm;
    float zrs = rsqrtf(zvr + 1e-5f);
    float zn = (tid < NNODE) ? ((zv - zm) * zrs * ln2g[tid] + ln2b[tid]) : 0.0f;
    float p0 = (tid < NNODE) ? zn * clsw[tid]         : 0.0f;
    float p1 = (tid < NNODE) ? zn * clsw[NNODE + tid] : 0.0f;
    float o0 = block_sum(p0, s_tmp);
    float o1 = block_sum(p1, s_tmp);
    if (tid == 0) {
        out[(size_t)b * 2 + 0] = o0 + clsb[0];
        out[(size_t)b * 2 + 1] = o1 + clsb[1];
    }
}

// ---------------------------------------------------------------------------
extern "C" void kernel_launch(void* const* d_in, const int* in_sizes, int n_in,
                              void* d_out, int out_size, void* d_ws, size_t ws_size,
                              hipStream_t stream) {
    const float* cli   = (const float*)d_in[0];
    const float* radio = (const float*)d_in[1];
    const int*   ei    = (const int*)d_in[2];
    const float* ln1g = (const float*)d_in[3];
    const float* ln1b = (const float*)d_in[4];
    const float* encw = (const float*)d_in[5];
    const float* encb = (const float*)d_in[6];
    const float* q1w  = (const float*)d_in[7];
    const float* q1b  = (const float*)d_in[8];
    const float* k1w  = (const float*)d_in[9];
    const float* k1b  = (const float*)d_in[10];
    const float* v1w  = (const float*)d_in[11];
    const float* v1b  = (const float*)d_in[12];
    const float* s1w  = (const float*)d_in[13];
    const float* s1b  = (const float*)d_in[14];
    const float* q2w  = (const float*)d_in[15];
    const float* q2b  = (const float*)d_in[16];
    const float* k2w  = (const float*)d_in[17];
    const float* k2b  = (const float*)d_in[18];
    const float* v2w  = (const float*)d_in[19];
    const float* v2b  = (const float*)d_in[20];
    const float* s2w  = (const float*)d_in[21];
    const float* s2b  = (const float*)d_in[22];
    const float* ln2g = (const float*)d_in[23];
    const float* ln2b = (const float*)d_in[24];
    const float* clsw = (const float*)d_in[25];
    const float* clsb = (const float*)d_in[26];

    const int E  = in_sizes[2] / 2;
    const int Bn = in_sizes[0] / 58;

    int* row_ptr = (int*)d_ws;
    int* csr_src = row_ptr + 80;   // row_ptr uses 79, pad to 80 for alignment

    build_csr_kernel<<<1, 256, 0, stream>>>(ei, E, row_ptr, csr_src);

    size_t shmem = (size_t)E * sizeof(int);
    graph_fused_kernel<<<Bn, 128, shmem, stream>>>(
        cli, radio, ln1g, ln1b, encw, encb,
        q1w, q1b, k1w, k1b, v1w, v1b, s1w, s1b,
        q2w, q2b, k2w, k2b, v2w, v2b, s2w, s2b,
        ln2g, ln2b, clsw, clsb,
        row_ptr, csr_src, E, (float*)d_out);
}

// Round 2
// 171.516 us; speedup vs baseline: 1.2033x; 1.2033x over previous
//
#include <hip/hip_runtime.h>

#define LREL(x) ((x) > 0.0f ? (x) : 0.01f * (x))

constexpr int NNODE = 78;
constexpr int GPB   = 32;    // graphs per block (lane dimension)
constexpr int BLOCK = 512;   // 8 waves
constexpr int ROWS  = 16;    // BLOCK / GPB node-row streams
constexpr int NI    = 5;     // ceil(78/16) nodes per thread
constexpr int PADS  = 33;    // padded lane stride (bank-conflict-free)

// ---------------------------------------------------------------------------
// Kernel 1: build incoming-edge CSR from edge_index [2, E] (int32).
// ---------------------------------------------------------------------------
__global__ void build_csr_kernel(const int* __restrict__ ei, int E,
                                 int* __restrict__ row_ptr,
                                 int* __restrict__ csr_src) {
    __shared__ int cnt[NNODE];
    __shared__ int cur[NNODE];
    int tid = threadIdx.x;
    if (tid < NNODE) cnt[tid] = 0;
    __syncthreads();
    for (int e = tid; e < E; e += blockDim.x)
        atomicAdd(&cnt[ei[E + e]], 1);          // tgt = ei[1][e]
    __syncthreads();
    if (tid == 0) {
        int acc = 0;
        for (int n = 0; n < NNODE; ++n) {
            row_ptr[n] = acc;
            cur[n]     = acc;
            acc += cnt[n];
        }
        row_ptr[NNODE] = acc;
    }
    __syncthreads();
    for (int e = tid; e < E; e += blockDim.x) {
        int t   = ei[E + e];
        int pos = atomicAdd(&cur[t], 1);
        csr_src[pos] = ei[e];                   // src = ei[0][e]
    }
}

// ---------------------------------------------------------------------------
// Kernel 2: fused forward. Block = 32 graphs (lanes) x 16 node-rows.
// ---------------------------------------------------------------------------
__global__ __launch_bounds__(BLOCK, 2) void graph_fused_kernel(
    const float* __restrict__ cli,    // [B,58]
    const float* __restrict__ radio,  // [B,384]
    const float* __restrict__ ln1g, const float* __restrict__ ln1b,
    const float* __restrict__ encw, const float* __restrict__ encb,
    const float* __restrict__ q1w, const float* __restrict__ q1b,
    const float* __restrict__ k1w, const float* __restrict__ k1b,
    const float* __restrict__ v1w, const float* __restrict__ v1b,
    const float* __restrict__ s1w, const float* __restrict__ s1b,
    const float* __restrict__ q2w, const float* __restrict__ q2b,
    const float* __restrict__ k2w, const float* __restrict__ k2b,
    const float* __restrict__ v2w, const float* __restrict__ v2b,
    const float* __restrict__ s2w, const float* __restrict__ s2b,
    const float* __restrict__ ln2g, const float* __restrict__ ln2b,
    const float* __restrict__ clsw, const float* __restrict__ clsb,
    const int* __restrict__ row_ptr, const int* __restrict__ csr_src,
    int E, int Bn, float* __restrict__ out) {

    __shared__ float s_feat[NNODE * PADS];   // node features [node][graph]
    __shared__ float s_k2[NNODE * PADS];     // per-node k-dot, layer 2
    __shared__ float s_v2[NNODE * PADS];     // per-node v-dot, layer 2
    __shared__ float s_redA[ROWS * PADS];
    __shared__ float s_redB[ROWS * PADS];
    __shared__ float s_statM[PADS];
    __shared__ float s_statR[PADS];
    __shared__ int   s_rp[NNODE + 1];
    extern __shared__ int s_csr[];           // [E+1]

    const int tid  = threadIdx.x;
    const int lane = tid & 63;
    const int w    = tid >> 6;        // wave 0..7
    const int half = (tid >> 5) & 1;  // half-wave
    const int l32  = tid & 31;
    const int b    = blockIdx.x;

    // ---- stage CSR + row_ptr ----
    for (int i = tid; i < E; i += BLOCK) s_csr[i] = csr_src[i];
    if (tid == 0) s_csr[E] = 0;
    if (tid < NNODE + 1) s_rp[tid] = row_ptr[tid];

    // ---- stage cli: wave w handles graphs w*4 .. w*4+3 ----
#pragma unroll
    for (int gg = 0; gg < 4; ++gg) {
        int g = w * 4 + gg;
        long gidx = (long)b * GPB + g;
        if (lane < 58 && gidx < Bn)
            s_feat[lane * PADS + g] = cli[gidx * 58 + lane];
    }

    // ---- phase 0: LayerNorm(384) + encoder(384->20), half-wave per graph ----
    const float4* radio4 = (const float4*)radio;
    const float4* encw4  = (const float4*)encw;
    const float4* g14    = (const float4*)ln1g;
    const float4* b14    = (const float4*)ln1b;
    float4 xn0[3], xn1[3];
    int gl0, gl1;
    {
#pragma unroll
        for (int pp = 0; pp < 2; ++pp) {
            int g = w * 4 + pp * 2 + half;
            long gidx = (long)b * GPB + g;
            bool ok = gidx < Bn;
            float4* xn = pp ? xn1 : xn0;
            if (pp) gl1 = g; else gl0 = g;
            float s = 0.0f, q = 0.0f;
#pragma unroll
            for (int i = 0; i < 3; ++i) {
                float4 v = ok ? radio4[gidx * 96 + l32 + 32 * i]
                              : make_float4(0, 0, 0, 0);
                xn[i] = v;
                s += v.x + v.y + v.z + v.w;
                q += v.x * v.x + v.y * v.y + v.z * v.z + v.w * v.w;
            }
#pragma unroll
            for (int o = 16; o; o >>= 1) {
                s += __shfl_xor(s, o, 32);
                q += __shfl_xor(q, o, 32);
            }
            float mean = s * (1.0f / 384.0f);
            float var  = q * (1.0f / 384.0f) - mean * mean;
            float rstd = rsqrtf(var + 1e-5f);
#pragma unroll
            for (int i = 0; i < 3; ++i) {
                float4 gv = g14[l32 + 32 * i];
                float4 bv = b14[l32 + 32 * i];
                float4 v  = xn[i];
                v.x = (v.x - mean) * rstd * gv.x + bv.x;
                v.y = (v.y - mean) * rstd * gv.y + bv.y;
                v.z = (v.z - mean) * rstd * gv.z + bv.z;
                v.w = (v.w - mean) * rstd * gv.w + bv.w;
                xn[i] = v;
            }
        }
        for (int j = 0; j < 20; ++j) {
            float4 w0 = encw4[j * 96 + l32];
            float4 w1 = encw4[j * 96 + l32 + 32];
            float4 w2 = encw4[j * 96 + l32 + 64];
#pragma unroll
            for (int pp = 0; pp < 2; ++pp) {
                const float4* xn = pp ? xn1 : xn0;
                float p = xn[0].x * w0.x;
                p = fmaf(xn[0].y, w0.y, p); p = fmaf(xn[0].z, w0.z, p);
                p = fmaf(xn[0].w, w0.w, p);
                p = fmaf(xn[1].x, w1.x, p); p = fmaf(xn[1].y, w1.y, p);
                p = fmaf(xn[1].z, w1.z, p); p = fmaf(xn[1].w, w1.w, p);
                p = fmaf(xn[2].x, w2.x, p); p = fmaf(xn[2].y, w2.y, p);
                p = fmaf(xn[2].z, w2.z, p); p = fmaf(xn[2].w, w2.w, p);
#pragma unroll
                for (int o = 16; o; o >>= 1) p += __shfl_xor(p, o, 32);
                if (l32 == j)
                    s_feat[(58 + j) * PADS + (pp ? gl1 : gl0)] =
                        LREL(p + encb[j]);
            }
        }
    }
    __syncthreads();

    // ---- conv phases: lane = graph, row stream r ----
    const int g = tid & 31;
    const int r = tid >> 5;               // 0..15
    const long gbase = (long)b * GPB + g;
    const bool gok = gbase < Bn;

    const float Q1W0 = q1w[0], Q1W1 = q1w[1], Q1W2 = q1w[2], Q1W3 = q1w[3];
    const float Q1B0 = q1b[0], Q1B1 = q1b[1], Q1B2 = q1b[2], Q1B3 = q1b[3];
    const float K1W0 = k1w[0], K1W1 = k1w[1], K1W2 = k1w[2], K1W3 = k1w[3];
    const float K1B0 = k1b[0], K1B1 = k1b[1], K1B2 = k1b[2], K1B3 = k1b[3];
    const float V1W0 = v1w[0], V1W1 = v1w[1], V1W2 = v1w[2], V1W3 = v1w[3];
    const float V1B0 = v1b[0], V1B1 = v1b[1], V1B2 = v1b[2], V1B3 = v1b[3];
    const float S1W0 = s1w[0], S1W1 = s1w[1], S1W2 = s1w[2], S1W3 = s1w[3];
    const float S1B0 = s1b[0], S1B1 = s1b[1], S1B2 = s1b[2], S1B3 = s1b[3];
    const float Q2W0 = q2w[0], Q2W1 = q2w[1], Q2W2 = q2w[2], Q2W3 = q2w[3];
    const float K2W0 = k2w[0], K2W1 = k2w[1], K2W2 = k2w[2], K2W3 = k2w[3];
    const float V2W0 = v2w[0], V2W1 = v2w[1], V2W2 = v2w[2], V2W3 = v2w[3];
    const float S2W0 = s2w[0], S2W1 = s2w[1], S2W2 = s2w[2], S2W3 = s2w[3];
    const float Q2B = q2b[0], K2B = k2b[0], V2B = v2b[0], S2B = s2b[0];

    float y_q[NI], y_sk[NI];

    // ---- TransformerConv 1 (H=4, C=1), single-pass softmax (|alpha|<~45) ----
#pragma unroll
    for (int k = 0; k < NI; ++k) {
        int n = r + ROWS * k;
        bool act = n < NNODE;
        int nn = act ? n : 0;
        float xv = s_feat[nn * PADS + g];
        float qh0 = fmaf(xv, Q1W0, Q1B0), qh1 = fmaf(xv, Q1W1, Q1B1);
        float qh2 = fmaf(xv, Q1W2, Q1B2), qh3 = fmaf(xv, Q1W3, Q1B3);
        float qa0 = qh0 * K1W0, cc0 = qh0 * K1B0;
        float qa1 = qh1 * K1W1, cc1 = qh1 * K1B1;
        float qa2 = qh2 * K1W2, cc2 = qh2 * K1B2;
        float qa3 = qh3 * K1W3, cc3 = qh3 * K1B3;
        float den0 = 0, den1 = 0, den2 = 0, den3 = 0;
        float wa0 = 0, wa1 = 0, wa2 = 0, wa3 = 0;
        int beg = s_rp[nn];
        int end = act ? s_rp[nn + 1] : beg;
        int i = beg;
        int sc = s_csr[i];
        while (i < end) {
            int sn = s_csr[i + 1];
            float t = s_feat[sc * PADS + g];
            float e0 = __expf(fmaf(qa0, t, cc0));
            float e1 = __expf(fmaf(qa1, t, cc1));
            float e2 = __expf(fmaf(qa2, t, cc2));
            float e3 = __expf(fmaf(qa3, t, cc3));
            den0 += e0; den1 += e1; den2 += e2; den3 += e3;
            wa0 = fmaf(e0, t, wa0); wa1 = fmaf(e1, t, wa1);
            wa2 = fmaf(e2, t, wa2); wa3 = fmaf(e3, t, wa3);
            sc = sn; ++i;
        }
        float y0 = LREL(fmaf(V1W0, wa0 / den0, V1B0) + fmaf(xv, S1W0, S1B0));
        float y1 = LREL(fmaf(V1W1, wa1 / den1, V1B1) + fmaf(xv, S1W1, S1B1));
        float y2 = LREL(fmaf(V1W2, wa2 / den2, V1B2) + fmaf(xv, S1W2, S1B2));
        float y3 = LREL(fmaf(V1W3, wa3 / den3, V1B3) + fmaf(xv, S1W3, S1B3));
        y_q[k]  = Q2B + y0 * Q2W0 + y1 * Q2W1 + y2 * Q2W2 + y3 * Q2W3;
        y_sk[k] = S2B + y0 * S2W0 + y1 * S2W1 + y2 * S2W2 + y3 * S2W3;
        float kk = K2B + y0 * K2W0 + y1 * K2W1 + y2 * K2W2 + y3 * K2W3;
        float vv = V2B + y0 * V2W0 + y1 * V2W1 + y2 * V2W2 + y3 * V2W3;
        if (act) {
            s_k2[n * PADS + g] = kk;
            s_v2[n * PADS + g] = vv;
        }
    }
    __syncthreads();

    // ---- TransformerConv 2 (H=1, C=1), two-pass softmax ----
    float z[NI];
    float zs = 0, zq = 0;
#pragma unroll
    for (int k = 0; k < NI; ++k) {
        int n = r + ROWS * k;
        bool act = n < NNODE;
        int nn = act ? n : 0;
        float q = y_q[k];
        int beg = s_rp[nn];
        int end = act ? s_rp[nn + 1] : beg;
        float m = -1e30f;
        int i = beg;
        int sc = s_csr[i];
        while (i < end) {
            int sn = s_csr[i + 1];
            m = fmaxf(m, q * s_k2[sc * PADS + g]);
            sc = sn; ++i;
        }
        float den = 0, acc = 0;
        i = beg;
        sc = s_csr[i];
        while (i < end) {
            int sn = s_csr[i + 1];
            float kk = s_k2[sc * PADS + g];
            float vv = s_v2[sc * PADS + g];
            float e = __expf(fmaf(q, kk, -m));
            den += e;
            acc = fmaf(e, vv, acc);
            sc = sn; ++i;
        }
        float zz = LREL(acc / den + y_sk[k]);
        z[k] = zz;
        if (act) { zs += zz; zq = fmaf(zz, zz, zq); }
    }

    // ---- final LayerNorm(78) + classifier ----
    s_redA[r * PADS + g] = zs;
    s_redB[r * PADS + g] = zq;
    __syncthreads();
    if (r == 0) {
        float a = 0, bb = 0;
#pragma unroll
        for (int i = 0; i < ROWS; ++i) {
            a  += s_redA[i * PADS + g];
            bb += s_redB[i * PADS + g];
        }
        float mean = a * (1.0f / 78.0f);
        float var  = bb * (1.0f / 78.0f) - mean * mean;
        s_statM[g] = mean;
        s_statR[g] = rsqrtf(var + 1e-5f);
    }
    __syncthreads();
    float mean = s_statM[g], rstd = s_statR[g];
    float p0 = 0, p1 = 0;
#pragma unroll
    for (int k = 0; k < NI; ++k) {
        int n = r + ROWS * k;
        if (n < NNODE) {
            float zn = fmaf((z[k] - mean) * rstd, ln2g[n], ln2b[n]);
            p0 = fmaf(zn, clsw[n], p0);
            p1 = fmaf(zn, clsw[NNODE + n], p1);
        }
    }
    __syncthreads();          // before reusing s_redA/B
    s_redA[r * PADS + g] = p0;
    s_redB[r * PADS + g] = p1;
    __syncthreads();
    if (r == 0 && gok) {
        float a = 0, bb = 0;
#pragma unroll
        for (int i = 0; i < ROWS; ++i) {
            a  += s_redA[i * PADS + g];
            bb += s_redB[i * PADS + g];
        }
        out[gbase * 2 + 0] = a + clsb[0];
        out[gbase * 2 + 1] = bb + clsb[1];
    }
}

// ---------------------------------------------------------------------------
extern "C" void kernel_launch(void* const* d_in, const int* in_sizes, int n_in,
                              void* d_out, int out_size, void* d_ws, size_t ws_size,
                              hipStream_t stream) {
    const float* cli   = (const float*)d_in[0];
    const float* radio = (const float*)d_in[1];
    const int*   ei    = (const int*)d_in[2];
    const float* ln1g = (const float*)d_in[3];
    const float* ln1b = (const float*)d_in[4];
    const float* encw = (const float*)d_in[5];
    const float* encb = (const float*)d_in[6];
    const float* q1w  = (const float*)d_in[7];
    const float* q1b  = (const float*)d_in[8];
    const float* k1w  = (const float*)d_in[9];
    const float* k1b  = (const float*)d_in[10];
    const float* v1w  = (const float*)d_in[11];
    const float* v1b  = (const float*)d_in[12];
    const float* s1w  = (const float*)d_in[13];
    const float* s1b  = (const float*)d_in[14];
    const float* q2w  = (const float*)d_in[15];
    const float* q2b  = (const float*)d_in[16];
    const float* k2w  = (const float*)d_in[17];
    const float* k2b  = (const float*)d_in[18];
    const float* v2w  = (const float*)d_in[19];
    const float* v2b  = (const float*)d_in[20];
    const float* s2w  = (const float*)d_in[21];
    const float* s2b  = (const float*)d_in[22];
    const float* ln2g = (const float*)d_in[23];
    const float* ln2b = (const float*)d_in[24];
    const float* clsw = (const float*)d_in[25];
    const float* clsb = (const float*)d_in[26];

    const int E  = in_sizes[2] / 2;
    const int Bn = in_sizes[0] / 58;

    int* row_ptr = (int*)d_ws;
    int* csr_src = row_ptr + 80;

    build_csr_kernel<<<1, 256, 0, stream>>>(ei, E, row_ptr, csr_src);

    const int grid = (Bn + GPB - 1) / GPB;
    size_t shmem = (size_t)(E + 1) * sizeof(int);
    graph_fused_kernel<<<grid, BLOCK, shmem, stream>>>(
        cli, radio, ln1g, ln1b, encw, encb,
        q1w, q1b, k1w, k1b, v1w, v1b, s1w, s1b,
        q2w, q2b, k2w, k2b, v2w, v2b, s2w, s2b,
        ln2g, ln2b, clsw, clsb,
        row_ptr, csr_src, E, Bn, (float*)d_out);
}

// Round 5
// 165.211 us; speedup vs baseline: 1.2493x; 1.0382x over previous
//
#include <hip/hip_runtime.h>

#define LREL(x) ((x) > 0.0f ? (x) : 0.01f * (x))
#define LOG2E 1.44269504f

constexpr int NNODE = 78;
constexpr int GPB   = 16;            // graphs per block (lane dimension)
constexpr int ROWS  = 32;            // node-row streams per graph
constexpr int BLOCK = GPB * ROWS;    // 512
constexpr int NI    = 3;             // ceil(78/32) node slots per thread
constexpr int PADS  = 17;            // padded lane stride

// ---------------------------------------------------------------------------
// Kernel 1: build incoming-edge CSR + degree-sorted slot permutation.
// csr entries pre-scaled by PADS. perm[96]: slot s -> node (-1 = empty).
// ---------------------------------------------------------------------------
__global__ void build_csr_kernel(const int* __restrict__ ei, int E,
                                 int* __restrict__ row_ptr,
                                 int* __restrict__ csr_src,
                                 int* __restrict__ perm) {
    __shared__ int cnt[NNODE];
    __shared__ int cur[NNODE];
    __shared__ int deg[NNODE];
    int tid = threadIdx.x;
    if (tid < NNODE) cnt[tid] = 0;
    __syncthreads();
    for (int e = tid; e < E; e += blockDim.x)
        atomicAdd(&cnt[ei[E + e]], 1);          // tgt = ei[1][e]
    __syncthreads();
    if (tid < NNODE) deg[tid] = cnt[tid];
    __syncthreads();
    if (tid == 0) {
        int acc = 0;
        for (int n = 0; n < NNODE; ++n) {
            row_ptr[n] = acc;
            cur[n]     = acc;
            acc += cnt[n];
        }
        row_ptr[NNODE] = acc;
    }
    if (tid < NNODE) {                          // parallel rank (desc by degree)
        int d = deg[tid], rank = 0;
        for (int m = 0; m < NNODE; ++m) {
            int dm = deg[m];
            rank += (dm > d) || (dm == d && m < tid);
        }
        perm[rank] = tid;
    }
    if (tid >= NNODE && tid < ROWS * NI) perm[tid] = -1;
    __syncthreads();
    for (int e = tid; e < E; e += blockDim.x) {
        int t   = ei[E + e];
        int pos = atomicAdd(&cur[t], 1);
        csr_src[pos] = ei[e] * PADS;            // pre-scaled src
    }
}

// ---------------------------------------------------------------------------
// Kernel 2: LayerNorm(384) + Linear(384->20) + leaky. h[B,20] to workspace.
// Block 256 = 4 waves; each half-wave handles 2 graphs (pp loop).
// ---------------------------------------------------------------------------
__global__ __launch_bounds__(256) void encode_kernel(
    const float* __restrict__ radio,
    const float* __restrict__ ln1g, const float* __restrict__ ln1b,
    const float* __restrict__ encw, const float* __restrict__ encb,
    int Bn, float* __restrict__ hout) {

    const int tid  = threadIdx.x;
    const int w    = tid >> 6;
    const int half = (tid >> 5) & 1;
    const int l32  = tid & 31;

    const float4* radio4 = (const float4*)radio;
    const float4* encw4  = (const float4*)encw;
    const float4* g14    = (const float4*)ln1g;
    const float4* b14    = (const float4*)ln1b;

    float4 xn0[3], xn1[3];
    const long g0 = (long)blockIdx.x * 16 + w * 4 + half;
    const long g1 = g0 + 2;

#pragma unroll
    for (int pp = 0; pp < 2; ++pp) {
        long gidx = pp ? g1 : g0;
        bool ok = gidx < Bn;
        float4* xn = pp ? xn1 : xn0;
        float s = 0.0f, q = 0.0f;
#pragma unroll
        for (int i = 0; i < 3; ++i) {
            float4 v = ok ? radio4[gidx * 96 + l32 + 32 * i]
                          : make_float4(0, 0, 0, 0);
            xn[i] = v;
            s += v.x + v.y + v.z + v.w;
            q += v.x * v.x + v.y * v.y + v.z * v.z + v.w * v.w;
        }
#pragma unroll
        for (int o = 16; o; o >>= 1) {
            s += __shfl_xor(s, o, 32);
            q += __shfl_xor(q, o, 32);
        }
        float mean = s * (1.0f / 384.0f);
        float var  = q * (1.0f / 384.0f) - mean * mean;
        float rstd = rsqrtf(var + 1e-5f);
#pragma unroll
        for (int i = 0; i < 3; ++i) {
            float4 gv = g14[l32 + 32 * i];
            float4 bv = b14[l32 + 32 * i];
            float4 v  = xn[i];
            v.x = (v.x - mean) * rstd * gv.x + bv.x;
            v.y = (v.y - mean) * rstd * gv.y + bv.y;
            v.z = (v.z - mean) * rstd * gv.z + bv.z;
            v.w = (v.w - mean) * rstd * gv.w + bv.w;
            xn[i] = v;
        }
    }

    float h0 = 0.0f, h1 = 0.0f;
    for (int j = 0; j < 20; ++j) {
        float4 w0 = encw4[j * 96 + l32];
        float4 w1 = encw4[j * 96 + l32 + 32];
        float4 w2 = encw4[j * 96 + l32 + 64];
#pragma unroll
        for (int pp = 0; pp < 2; ++pp) {
            const float4* xn = pp ? xn1 : xn0;
            float p = xn[0].x * w0.x;
            p = fmaf(xn[0].y, w0.y, p); p = fmaf(xn[0].z, w0.z, p);
            p = fmaf(xn[0].w, w0.w, p);
            p = fmaf(xn[1].x, w1.x, p); p = fmaf(xn[1].y, w1.y, p);
            p = fmaf(xn[1].z, w1.z, p); p = fmaf(xn[1].w, w1.w, p);
            p = fmaf(xn[2].x, w2.x, p); p = fmaf(xn[2].y, w2.y, p);
            p = fmaf(xn[2].w, w2.w, p); p = fmaf(xn[2].z, w2.z, p);
#pragma unroll
            for (int o = 16; o; o >>= 1) p += __shfl_xor(p, o, 32);
            if (pp) h1 = (l32 == j) ? p : h1;
            else    h0 = (l32 == j) ? p : h0;
        }
    }
    if (l32 < 20) {
        float eb = encb[l32];
        if (g0 < Bn) hout[g0 * 20 + l32] = LREL(h0 + eb);
        if (g1 < Bn) hout[g1 * 20 + l32] = LREL(h1 + eb);
    }
}

// ---------------------------------------------------------------------------
// Kernel 3: conv1 + conv2 + LN(78) + classifier. 16 graphs x 32 rows.
// ---------------------------------------------------------------------------
__global__ __launch_bounds__(BLOCK, 4) void graph_conv_kernel(
    const float* __restrict__ cli, const float* __restrict__ hin,
    const float* __restrict__ q1w, const float* __restrict__ q1b,
    const float* __restrict__ k1w, const float* __restrict__ k1b,
    const float* __restrict__ v1w, const float* __restrict__ v1b,
    const float* __restrict__ s1w, const float* __restrict__ s1b,
    const float* __restrict__ q2w, const float* __restrict__ q2b,
    const float* __restrict__ k2w, const float* __restrict__ k2b,
    const float* __restrict__ v2w, const float* __restrict__ v2b,
    const float* __restrict__ s2w, const float* __restrict__ s2b,
    const float* __restrict__ ln2g, const float* __restrict__ ln2b,
    const float* __restrict__ clsw, const float* __restrict__ clsb,
    const int* __restrict__ row_ptr, const int* __restrict__ csr_src,
    const int* __restrict__ perm,
    int E, int Bn, float* __restrict__ out) {

    __shared__ float s_feat[NNODE * PADS];
    __shared__ float s_k2[NNODE * PADS];
    __shared__ float s_v2[NNODE * PADS];
    __shared__ float s_redA[8 * PADS];
    __shared__ float s_redB[8 * PADS];
    __shared__ float s_statM[GPB];
    __shared__ float s_statR[GPB];
    __shared__ int   s_rp[NNODE + 1];
    __shared__ int   s_slot[ROWS * NI];
    extern __shared__ int s_csr[];

    const int tid  = threadIdx.x;
    const int g    = tid & 15;
    const int r    = tid >> 4;
    const int w    = tid >> 6;
    const int lane = tid & 63;
    const long base = (long)blockIdx.x * GPB;

    for (int i = tid; i < E; i += BLOCK) s_csr[i] = csr_src[i];
    if (tid < NNODE + 1) s_rp[tid] = row_ptr[tid];
    if (tid < ROWS * NI) s_slot[tid] = perm[tid];
    for (int idx = tid; idx < GPB * 58; idx += BLOCK) {
        int gg = idx / 58, c = idx - gg * 58;
        if (base + gg < Bn) s_feat[c * PADS + gg] = cli[(base + gg) * 58 + c];
    }
    if (tid < GPB * 20) {
        int gg = tid / 20, j = tid - gg * 20;
        if (base + gg < Bn) s_feat[(58 + j) * PADS + gg] = hin[(base + gg) * 20 + j];
    }

    const float Q1W0 = q1w[0], Q1W1 = q1w[1], Q1W2 = q1w[2], Q1W3 = q1w[3];
    const float Q1B0 = q1b[0], Q1B1 = q1b[1], Q1B2 = q1b[2], Q1B3 = q1b[3];
    const float K1L0 = k1w[0] * LOG2E, K1L1 = k1w[1] * LOG2E;
    const float K1L2 = k1w[2] * LOG2E, K1L3 = k1w[3] * LOG2E;
    const float V1W0 = v1w[0], V1W1 = v1w[1], V1W2 = v1w[2], V1W3 = v1w[3];
    const float V1B0 = v1b[0], V1B1 = v1b[1], V1B2 = v1b[2], V1B3 = v1b[3];
    const float S1W0 = s1w[0], S1W1 = s1w[1], S1W2 = s1w[2], S1W3 = s1w[3];
    const float S1B0 = s1b[0], S1B1 = s1b[1], S1B2 = s1b[2], S1B3 = s1b[3];
    const float Q2W0 = q2w[0], Q2W1 = q2w[1], Q2W2 = q2w[2], Q2W3 = q2w[3];
    const float K2W0 = k2w[0], K2W1 = k2w[1], K2W2 = k2w[2], K2W3 = k2w[3];
    const float V2W0 = v2w[0], V2W1 = v2w[1], V2W2 = v2w[2], V2W3 = v2w[3];
    const float S2W0 = s2w[0], S2W1 = s2w[1], S2W2 = s2w[2], S2W3 = s2w[3];
    const float Q2B = q2b[0], K2B = k2b[0], V2B = v2b[0], S2B = s2b[0];
    __syncthreads();

    int   nodes[NI];
    float y_q[NI], y_sk[NI], z[NI];

    // ---- TransformerConv 1 (H=4,C=1): single-pass, cc dropped (softmax shift) ----
#pragma unroll
    for (int k = 0; k < NI; ++k) {
        int n = s_slot[k * ROWS + r];
        nodes[k] = n;
        bool act = n >= 0;
        int nn = act ? n : 0;
        float xv = s_feat[nn * PADS + g];
        float qh0 = fmaf(xv, Q1W0, Q1B0), qh1 = fmaf(xv, Q1W1, Q1B1);
        float qh2 = fmaf(xv, Q1W2, Q1B2), qh3 = fmaf(xv, Q1W3, Q1B3);
        float qa0 = qh0 * K1L0, qa1 = qh1 * K1L1;
        float qa2 = qh2 * K1L2, qa3 = qh3 * K1L3;
        float den0 = 0, den1 = 0, den2 = 0, den3 = 0;
        float wa0 = 0, wa1 = 0, wa2 = 0, wa3 = 0;
        int beg = s_rp[nn];
        int end = act ? s_rp[nn + 1] : beg;
        int i = beg;
        for (; i + 1 < end; i += 2) {
            int c0 = s_csr[i], c1 = s_csr[i + 1];
            float t0 = s_feat[c0 + g];
            float t1 = s_feat[c1 + g];
            float ea0 = exp2f(qa0 * t0), eb0 = exp2f(qa0 * t1);
            float ea1 = exp2f(qa1 * t0), eb1 = exp2f(qa1 * t1);
            float ea2 = exp2f(qa2 * t0), eb2 = exp2f(qa2 * t1);
            float ea3 = exp2f(qa3 * t0), eb3 = exp2f(qa3 * t1);
            den0 += ea0 + eb0; den1 += ea1 + eb1;
            den2 += ea2 + eb2; den3 += ea3 + eb3;
            wa0 = fmaf(ea0, t0, fmaf(eb0, t1, wa0));
            wa1 = fmaf(ea1, t0, fmaf(eb1, t1, wa1));
            wa2 = fmaf(ea2, t0, fmaf(eb2, t1, wa2));
            wa3 = fmaf(ea3, t0, fmaf(eb3, t1, wa3));
        }
        if (i < end) {
            int c0 = s_csr[i];
            float t0 = s_feat[c0 + g];
            float ea0 = exp2f(qa0 * t0), ea1 = exp2f(qa1 * t0);
            float ea2 = exp2f(qa2 * t0), ea3 = exp2f(qa3 * t0);
            den0 += ea0; den1 += ea1; den2 += ea2; den3 += ea3;
            wa0 = fmaf(ea0, t0, wa0); wa1 = fmaf(ea1, t0, wa1);
            wa2 = fmaf(ea2, t0, wa2); wa3 = fmaf(ea3, t0, wa3);
        }
        float y0 = LREL(fmaf(V1W0, wa0 / den0, V1B0) + fmaf(xv, S1W0, S1B0));
        float y1 = LREL(fmaf(V1W1, wa1 / den1, V1B1) + fmaf(xv, S1W1, S1B1));
        float y2 = LREL(fmaf(V1W2, wa2 / den2, V1B2) + fmaf(xv, S1W2, S1B2));
        float y3 = LREL(fmaf(V1W3, wa3 / den3, V1B3) + fmaf(xv, S1W3, S1B3));
        y_q[k]  = Q2B + y0 * Q2W0 + y1 * Q2W1 + y2 * Q2W2 + y3 * Q2W3;
        y_sk[k] = S2B + y0 * S2W0 + y1 * S2W1 + y2 * S2W2 + y3 * S2W3;
        if (act) {
            s_k2[n * PADS + g] = K2B + y0 * K2W0 + y1 * K2W1 + y2 * K2W2 + y3 * K2W3;
            s_v2[n * PADS + g] = V2B + y0 * V2W0 + y1 * V2W1 + y2 * V2W2 + y3 * V2W3;
        }
    }
    __syncthreads();

    // ---- TransformerConv 2 (H=1,C=1): two-pass softmax ----
    float zs = 0, zq = 0;
#pragma unroll
    for (int k = 0; k < NI; ++k) {
        int n = nodes[k];
        bool act = n >= 0;
        int nn = act ? n : 0;
        float q = y_q[k];
        int beg = s_rp[nn];
        int end = act ? s_rp[nn + 1] : beg;
        float m = -1e30f;
        for (int i = beg; i < end; ++i)
            m = fmaxf(m, q * s_k2[s_csr[i] + g]);
        float ql = q * LOG2E, ml = m * LOG2E;
        float den = 0, acc = 0;
        int i = beg;
        for (; i + 1 < end; i += 2) {
            int c0 = s_csr[i], c1 = s_csr[i + 1];
            float k0 = s_k2[c0 + g], k1v = s_k2[c1 + g];
            float v0 = s_v2[c0 + g], v1v = s_v2[c1 + g];
            float e0 = exp2f(fmaf(ql, k0, -ml));
            float e1 = exp2f(fmaf(ql, k1v, -ml));
            den += e0 + e1;
            acc = fmaf(e0, v0, fmaf(e1, v1v, acc));
        }
        if (i < end) {
            int c0 = s_csr[i];
            float e0 = exp2f(fmaf(ql, s_k2[c0 + g], -ml));
            den += e0;
            acc = fmaf(e0, s_v2[c0 + g], acc);
        }
        float zz = LREL(acc / den + y_sk[k]);
        z[k] = zz;
        if (act) { zs += zz; zq = fmaf(zz, zz, zq); }
    }

    // ---- final LayerNorm(78) + classifier ----
    zs += __shfl_xor(zs, 16, 64); zs += __shfl_xor(zs, 32, 64);
    zq += __shfl_xor(zq, 16, 64); zq += __shfl_xor(zq, 32, 64);
    if (lane < 16) {
        s_redA[w * PADS + lane] = zs;
        s_redB[w * PADS + lane] = zq;
    }
    __syncthreads();
    if (tid < GPB) {
        float a = 0, bb = 0;
#pragma unroll
        for (int i = 0; i < 8; ++i) {
            a  += s_redA[i * PADS + tid];
            bb += s_redB[i * PADS + tid];
        }
        float mean = a * (1.0f / 78.0f);
        float var  = bb * (1.0f / 78.0f) - mean * mean;
        s_statM[tid] = mean;
        s_statR[tid] = rsqrtf(var + 1e-5f);
    }
    __syncthreads();
    float mean = s_statM[g], rstd = s_statR[g];
    float p0 = 0, p1 = 0;
#pragma unroll
    for (int k = 0; k < NI; ++k) {
        int n = nodes[k];
        if (n >= 0) {
            float zn = fmaf((z[k] - mean) * rstd, ln2g[n], ln2b[n]);
            p0 = fmaf(zn, clsw[n], p0);
            p1 = fmaf(zn, clsw[NNODE + n], p1);
        }
    }
    p0 += __shfl_xor(p0, 16, 64); p0 += __shfl_xor(p0, 32, 64);
    p1 += __shfl_xor(p1, 16, 64); p1 += __shfl_xor(p1, 32, 64);
    if (lane < 16) {
        s_redA[w * PADS + lane] = p0;
        s_redB[w * PADS + lane] = p1;
    }
    __syncthreads();
    if (tid < GPB) {
        float a = 0, bb = 0;
#pragma unroll
        for (int i = 0; i < 8; ++i) {
            a  += s_redA[i * PADS + tid];
            bb += s_redB[i * PADS + tid];
        }
        long gi = base + tid;
        if (gi < Bn) {
            out[gi * 2 + 0] = a + clsb[0];
            out[gi * 2 + 1] = bb + clsb[1];
        }
    }
}

// ---------------------------------------------------------------------------
extern "C" void kernel_launch(void* const* d_in, const int* in_sizes, int n_in,
                              void* d_out, int out_size, void* d_ws, size_t ws_size,
                              hipStream_t stream) {
    const float* cli   = (const float*)d_in[0];
    const float* radio = (const float*)d_in[1];
    const int*   ei    = (const int*)d_in[2];
    const float* ln1g = (const float*)d_in[3];
    const float* ln1b = (const float*)d_in[4];
    const float* encw = (const float*)d_in[5];
    const float* encb = (const float*)d_in[6];
    const float* q1w  = (const float*)d_in[7];
    const float* q1b  = (const float*)d_in[8];
    const float* k1w  = (const float*)d_in[9];
    const float* k1b  = (const float*)d_in[10];
    const float* v1w  = (const float*)d_in[11];
    const float* v1b  = (const float*)d_in[12];
    const float* s1w  = (const float*)d_in[13];
    const float* s1b  = (const float*)d_in[14];
    const float* q2w  = (const float*)d_in[15];
    const float* q2b  = (const float*)d_in[16];
    const float* k2w  = (const float*)d_in[17];
    const float* k2b  = (const float*)d_in[18];
    const float* v2w  = (const float*)d_in[19];
    const float* v2b  = (const float*)d_in[20];
    const float* s2w  = (const float*)d_in[21];
    const float* s2b  = (const float*)d_in[22];
    const float* ln2g = (const float*)d_in[23];
    const float* ln2b = (const float*)d_in[24];
    const float* clsw = (const float*)d_in[25];
    const float* clsb = (const float*)d_in[26];

    const int E  = in_sizes[2] / 2;
    const int Bn = in_sizes[0] / 58;

    int* row_ptr = (int*)d_ws;
    int* csr_src = row_ptr + 80;
    int* perm    = csr_src + E;
    int  off     = (80 + E + ROWS * NI + 7) & ~7;
    float* h     = (float*)((int*)d_ws + off);

    build_csr_kernel<<<1, 256, 0, stream>>>(ei, E, row_ptr, csr_src, perm);

    const int egrid = (Bn + 15) / 16;
    encode_kernel<<<egrid, 256, 0, stream>>>(radio, ln1g, ln1b, encw, encb, Bn, h);

    const int grid = (Bn + GPB - 1) / GPB;
    size_t shmem = (size_t)E * sizeof(int);
    graph_conv_kernel<<<grid, BLOCK, shmem, stream>>>(
        cli, h,
        q1w, q1b, k1w, k1b, v1w, v1b, s1w, s1b,
        q2w, q2b, k2w, k2b, v2w, v2b, s2w, s2b,
        ln2g, ln2b, clsw, clsb,
        row_ptr, csr_src, perm, E, Bn, (float*)d_out);
}